// Round 6
// baseline (569.696 us; speedup 1.0000x reference)
//
#include <hip/hip_runtime.h>
#include <stdint.h>

#define D 128

typedef unsigned int u32;
typedef unsigned short u16;

static __device__ __forceinline__ float bf2f(u16 h) {
    return __uint_as_float(((u32)h) << 16);
}

// ---------------- probe input widths ----------------
// flags[0] = 1 if item_emb/biases are bf16, 0 if fp32
// flags[1] = 1 if edge_index is int64, 0 if int32
// flags[2] = 1 if weights are bf16, 0 if fp32
__global__ void k_probe(const u16* __restrict__ emb_raw, const u32* __restrict__ ei_raw,
                        const u16* __restrict__ w_raw, int* __restrict__ flags) {
    if (threadIdx.x != 0) return;
    auto sane_bf16 = [](const u16* p) {
        int sane = 0;
        for (int i = 0; i < 256; i++) {
            u16 h = p[2 * i];            // even u16 slots
            u32 ex = (h >> 7) & 0xFF;    // bf16 exponent field
            if (h == 0 || (ex >= 0x60 && ex <= 0x8F)) sane++;
        }
        return sane >= 200;
    };
    flags[0] = sane_bf16(emb_raw) ? 1 : 0;
    flags[2] = sane_bf16(w_raw) ? 1 : 0;
    int zeros = 0;
    for (int i = 0; i < 256; i++)
        if (ei_raw[2 * i + 1] == 0) zeros++;  // high words of int64 ~always zero
    flags[1] = (zeros >= 200) ? 1 : 0;
}

static __device__ __forceinline__ int load_edge(const u32* __restrict__ ei, int is64,
                                                size_t flat_idx, int n) {
    int v = is64 ? (int)ei[2 * flat_idx] : (int)ei[flat_idx];
    if (v < 0) v = 0;          // clamp: memory safety even on mis-probe
    if (v >= n) v = n - 1;
    return v;
}

// ---------------- zero ----------------
__global__ void k_zero(int* __restrict__ p, int count) {
    int i = blockIdx.x * 256 + threadIdx.x;
    if (i < count) p[i] = 0;
}

// ---------------- degree histogram over dst ----------------
__global__ void k_hist(const u32* __restrict__ ei, int E, int n,
                       const int* __restrict__ flags, int* __restrict__ hist) {
    int e = blockIdx.x * 256 + threadIdx.x;
    if (e >= E) return;
    int d = load_edge(ei, flags[1], (size_t)E + e, n);
    atomicAdd(&hist[d], 1);
}

// ---------------- scan (3-kernel exclusive scan over n bins) ----------------
__global__ void k_scan1(const int* __restrict__ hist, int n,
                        int* __restrict__ incl, int* __restrict__ bsums) {
    __shared__ int s[256];
    int t = threadIdx.x;
    int i = blockIdx.x * 256 + t;
    int v = (i < n) ? hist[i] : 0;
    s[t] = v;
    __syncthreads();
    for (int d2 = 1; d2 < 256; d2 <<= 1) {
        int add = (t >= d2) ? s[t - d2] : 0;
        __syncthreads();
        s[t] += add;
        __syncthreads();
    }
    if (i < n) incl[i] = s[t];
    if (t == 255) bsums[blockIdx.x] = s[255];
}

__global__ void k_scan2(int* __restrict__ bsums, int nb) {
    __shared__ int s[256];
    int t = threadIdx.x;
    int v = (t < nb) ? bsums[t] : 0;
    s[t] = v;
    __syncthreads();
    for (int d2 = 1; d2 < 256; d2 <<= 1) {
        int add = (t >= d2) ? s[t - d2] : 0;
        __syncthreads();
        s[t] += add;
        __syncthreads();
    }
    if (t < nb) bsums[t] = s[t];
}

__global__ void k_scan3(const int* __restrict__ hist, const int* __restrict__ bsums,
                        int n, int* __restrict__ csr_off, float* __restrict__ dinv) {
    int i = blockIdx.x * 256 + threadIdx.x;
    if (i >= n) return;
    int b = blockIdx.x;
    int add = (b > 0) ? bsums[b - 1] : 0;
    int h = hist[i];
    csr_off[i] = add + csr_off[i] - h;  // csr_off held per-block inclusive scan
    dinv[i] = rsqrtf((float)(h + 1));   // +1 self-loop; deg always > 0
}

// ---------------- scatter edges into CSR (by dst), precompute norm ----------------
__global__ void k_scatter(const u32* __restrict__ ei, int E, int n,
                          const int* __restrict__ flags,
                          const int* __restrict__ csr_off, int* __restrict__ csr_pos,
                          const float* __restrict__ dinv,
                          int* __restrict__ csr_src, float* __restrict__ csr_norm) {
    int e = blockIdx.x * 256 + threadIdx.x;
    if (e >= E) return;
    int is64 = flags[1];
    int s = load_edge(ei, is64, (size_t)e, n);
    int d = load_edge(ei, is64, (size_t)E + e, n);
    int p = csr_off[d] + atomicAdd(&csr_pos[d], 1);
    if (p >= E) p = E - 1;  // safety clamp
    csr_src[p] = s;
    csr_norm[p] = dinv[s] * dinv[d];
}

// ---------------- x0: out slot1 = fp32(item_emb[-n:]) ----------------
__global__ void k_x0(const void* __restrict__ emb, int off_elems, int nD4,
                     const int* __restrict__ flags, float* __restrict__ out_x0) {
    int i = blockIdx.x * 256 + threadIdx.x;
    if (i >= nD4) return;
    float4 v;
    if (flags[0]) {  // bf16 input
        ushort4 h = ((const ushort4*)((const u16*)emb + off_elems))[i];
        v = make_float4(bf2f(h.x), bf2f(h.y), bf2f(h.z), bf2f(h.w));
    } else {         // fp32 input
        v = ((const float4*)((const float*)emb + off_elems))[i];
    }
    ((float4*)out_x0)[i] = v;
}

// ---------------- GEMM: Y[n x 128] = A[n x 128] (fp32) @ W_l[128 x 128] ----------------
// block 256 threads, 64 rows/block; W staged fp32 in LDS (64KB).
// thread (rowg=tid>>4, colg=tid&15): rows rowg*4..+3, cols {colg+16j, j=0..7}
// -> LDS reads of W broadcast across rowg, conflict-free across colg.
__global__ __launch_bounds__(256) void k_gemm(const float* __restrict__ A,
                                              const void* __restrict__ Wbase, int layer,
                                              const int* __restrict__ flags, int n,
                                              float* __restrict__ Y) {
    __shared__ float Ws[D * D];  // 64 KB
    int tid = threadIdx.x;
    const size_t woff = (size_t)layer * D * D;  // element offset of W_l
    if (flags[2]) {  // bf16 weights
        const ushort4* w4 = (const ushort4*)((const u16*)Wbase + woff);
#pragma unroll
        for (int j = 0; j < 16; j++) {
            int e = j * 1024 + tid * 4;
            ushort4 h = w4[j * 256 + tid];
            Ws[e + 0] = bf2f(h.x);
            Ws[e + 1] = bf2f(h.y);
            Ws[e + 2] = bf2f(h.z);
            Ws[e + 3] = bf2f(h.w);
        }
    } else {         // fp32 weights
        const float4* w4 = (const float4*)((const float*)Wbase + woff);
#pragma unroll
        for (int j = 0; j < 16; j++) {
            int e = j * 1024 + tid * 4;
            float4 v = w4[j * 256 + tid];
            Ws[e + 0] = v.x;
            Ws[e + 1] = v.y;
            Ws[e + 2] = v.z;
            Ws[e + 3] = v.w;
        }
    }
    __syncthreads();

    int rowg = tid >> 4, colg = tid & 15;
    int row0 = blockIdx.x * 64 + rowg * 4;

    float acc[4][8];
#pragma unroll
    for (int r = 0; r < 4; r++)
#pragma unroll
        for (int j = 0; j < 8; j++) acc[r][j] = 0.0f;

    const float4* a4[4];
#pragma unroll
    for (int r = 0; r < 4; r++) {
        int rr = row0 + r;
        if (rr >= n) rr = 0;  // dummy row; stores guarded below
        a4[r] = (const float4*)(A + (size_t)rr * D);
    }

    for (int kk = 0; kk < 32; kk++) {
        float av[4][4];
#pragma unroll
        for (int r = 0; r < 4; r++) {
            float4 t = a4[r][kk];
            av[r][0] = t.x; av[r][1] = t.y; av[r][2] = t.z; av[r][3] = t.w;
        }
#pragma unroll
        for (int e = 0; e < 4; e++) {
            int k = kk * 4 + e;
            float w[8];
#pragma unroll
            for (int j = 0; j < 8; j++) w[j] = Ws[k * D + colg + 16 * j];
#pragma unroll
            for (int r = 0; r < 4; r++)
#pragma unroll
                for (int j = 0; j < 8; j++) acc[r][j] += av[r][e] * w[j];
        }
    }

#pragma unroll
    for (int r = 0; r < 4; r++) {
        int rr = row0 + r;
        if (rr < n) {
#pragma unroll
            for (int j = 0; j < 8; j++)
                Y[(size_t)rr * D + colg + 16 * j] = acc[r][j];
        }
    }
}

// ---------------- aggregation: one block (128 thr) per dst node ----------------
__global__ __launch_bounds__(128) void k_agg(const float* __restrict__ Y,
                                             const int* __restrict__ csr_off,
                                             const int* __restrict__ cnt,
                                             const int* __restrict__ csr_src,
                                             const float* __restrict__ csr_norm,
                                             const float* __restrict__ dinv,
                                             const void* __restrict__ bias_base, int layer,
                                             const int* __restrict__ flags,
                                             float* __restrict__ out_x) {
    int i = blockIdx.x;
    int t = threadIdx.x;
    __shared__ int s_src[128];
    __shared__ float s_w[128];

    float di = dinv[i];
    float acc = Y[(size_t)i * D + t] * (di * di);  // self-loop
    float acc2 = 0.0f;
    int start = csr_off[i];
    int c = cnt[i];

    for (int b = 0; b < c; b += 128) {
        int m = c - b;
        if (m > 128) m = 128;
        __syncthreads();
        if (t < m) {
            s_src[t] = csr_src[start + b + t];
            s_w[t] = csr_norm[start + b + t];
        }
        __syncthreads();
        int k = 0;
        for (; k + 1 < m; k += 2) {
            acc  += Y[(size_t)s_src[k] * D + t] * s_w[k];
            acc2 += Y[(size_t)s_src[k + 1] * D + t] * s_w[k + 1];
        }
        if (k < m) acc += Y[(size_t)s_src[k] * D + t] * s_w[k];
    }
    int boff = layer * D + t;
    float bv = flags[0] ? bf2f(((const u16*)bias_base)[boff])
                        : ((const float*)bias_base)[boff];
    out_x[(size_t)i * D + t] = acc + acc2 + bv;
}

// ---------------- total = x0+x1+x2+x3 (fp32) ----------------
__global__ void k_total(const float* __restrict__ out_base, int nD4,
                        float* __restrict__ out_tot) {
    int i = blockIdx.x * 256 + threadIdx.x;
    if (i >= nD4) return;
    size_t nD = (size_t)nD4 * 4;
    float4 s = make_float4(0.f, 0.f, 0.f, 0.f);
#pragma unroll
    for (int q = 1; q <= 4; q++) {
        float4 h = ((const float4*)(out_base + q * nD))[i];
        s.x += h.x; s.y += h.y; s.z += h.z; s.w += h.w;
    }
    ((float4*)out_tot)[i] = s;
}

extern "C" void kernel_launch(void* const* d_in, const int* in_sizes, int n_in,
                              void* d_out, int out_size, void* d_ws, size_t ws_size,
                              hipStream_t stream) {
    float* out = (float*)d_out;              // fp32: [total, x0, x1, x2, x3], each n*128

    const int n = out_size / (5 * D);        // 50000

    // inputs identified by element count (robust to ordering; == dict order here)
    int i_emb = -1, i_ei = -1, i_w = -1, i_b = -1;
    {
        int order[8];
        int m = n_in > 8 ? 8 : n_in;
        for (int i = 0; i < m; i++) order[i] = i;
        for (int a = 0; a < m; a++)
            for (int b2 = a + 1; b2 < m; b2++)
                if (in_sizes[order[b2]] > in_sizes[order[a]]) {
                    int tmp = order[a]; order[a] = order[b2]; order[b2] = tmp;
                }
        i_emb = order[0];
        i_ei  = (m > 1) ? order[1] : 0;
        for (int i = 0; i < m; i++) {
            if (in_sizes[i] == 3 * D * D && i_w < 0) i_w = i;
            if (in_sizes[i] == 3 * D && i_b < 0) i_b = i;
        }
        if (i_w < 0) i_w = (m > 2) ? order[2] : 0;
        if (i_b < 0) i_b = (m > 3) ? order[3] : 0;
    }
    const void* emb  = d_in[i_emb];
    const void* wts  = d_in[i_w];
    const void* bias = d_in[i_b];
    const u32*  ei   = (const u32*)d_in[i_ei];

    const int E = in_sizes[i_ei] / 2;        // 600000
    const int rows = in_sizes[i_emb] / D;    // 80000
    const int off_elems = (rows - n) * D;    // item_emb[-n:]

    char* p = (char*)d_ws;
    auto take = [&](size_t bytes) {
        char* r = p;
        p += (bytes + 255) & ~(size_t)255;
        return r;
    };
    int*   flags    = (int*)  take(3 * 4);
    int*   hist     = (int*)  take((size_t)n * 4);
    int*   csr_pos  = (int*)  take((size_t)n * 4);
    int*   csr_off  = (int*)  take((size_t)n * 4);
    int*   bsums    = (int*)  take(256 * 4);
    float* dinv     = (float*)take((size_t)n * 4);
    int*   csr_src  = (int*)  take((size_t)E * 4);
    float* csr_norm = (float*)take((size_t)E * 4);
    // total ws: ~5.6 MB. Y scratch = out slot 0 (fp32 nD floats, free until k_total).

    const int nD = n * D;
    const int nb = (n + 255) / 256;          // 196 (<=256 required by k_scan2)
    const int eb = (E + 255) / 256;
    float* ybuf = out;                       // slot 0 as fp32 scratch

    k_probe<<<1, 64, 0, stream>>>((const u16*)emb, ei, (const u16*)wts, flags);
    k_zero<<<nb, 256, 0, stream>>>(hist, n);
    k_zero<<<nb, 256, 0, stream>>>(csr_pos, n);
    k_hist<<<eb, 256, 0, stream>>>(ei, E, n, flags, hist);
    k_scan1<<<nb, 256, 0, stream>>>(hist, n, csr_off, bsums);
    k_scan2<<<1, 256, 0, stream>>>(bsums, nb);
    k_scan3<<<nb, 256, 0, stream>>>(hist, bsums, n, csr_off, dinv);
    k_scatter<<<eb, 256, 0, stream>>>(ei, E, n, flags, csr_off, csr_pos, dinv,
                                      csr_src, csr_norm);
    k_x0<<<(nD / 4 + 255) / 256, 256, 0, stream>>>(emb, off_elems, nD / 4, flags,
                                                   out + (size_t)nD);

    for (int l = 0; l < 3; l++) {
        const float* A = out + (size_t)(1 + l) * nD;   // x_l slot (fp32)
        float* ox = out + (size_t)(2 + l) * nD;        // x_{l+1} slot
        k_gemm<<<(n + 63) / 64, 256, 0, stream>>>(A, wts, l, flags, n, ybuf);
        k_agg<<<n, 128, 0, stream>>>(ybuf, csr_off, hist, csr_src, csr_norm,
                                     dinv, bias, l, flags, ox);
    }
    k_total<<<(nD / 4 + 255) / 256, 256, 0, stream>>>(out, nD / 4, out);
}

// Round 7
// 466.888 us; speedup vs baseline: 1.2202x; 1.2202x over previous
//
#include <hip/hip_runtime.h>
#include <stdint.h>

#define D 128

typedef unsigned int u32;
typedef unsigned short u16;

static __device__ __forceinline__ float bf2f(u16 h) {
    return __uint_as_float(((u32)h) << 16);
}
static __device__ __forceinline__ u16 f2bf(float f) {
    u32 u = __float_as_uint(f);
    u32 r = (u + 0x7fffu + ((u >> 16) & 1u)) >> 16;  // round-to-nearest-even
    return (u16)r;
}

// ---------------- probe input widths (64-lane parallel) ----------------
// flags[0]=1 if item_emb/biases bf16 else fp32; flags[1]=1 if edges int64 else int32;
// flags[2]=1 if weights bf16 else fp32
__global__ void k_probe(const u16* __restrict__ emb_raw, const u32* __restrict__ ei_raw,
                        const u16* __restrict__ w_raw, int* __restrict__ flags) {
    int t = threadIdx.x;  // 64
    int se = 0, sw = 0, zz = 0;
#pragma unroll
    for (int q = 0; q < 4; q++) {
        int i = t * 4 + q;  // 256 samples
        u16 he = emb_raw[2 * i];
        u32 exe = (he >> 7) & 0xFF;
        if (he == 0 || (exe >= 0x60 && exe <= 0x8F)) se++;
        u16 hw = w_raw[2 * i];
        u32 exw = (hw >> 7) & 0xFF;
        if (hw == 0 || (exw >= 0x60 && exw <= 0x8F)) sw++;
        if (ei_raw[2 * i + 1] == 0) zz++;
    }
#pragma unroll
    for (int o = 32; o; o >>= 1) {
        se += __shfl_down(se, o);
        sw += __shfl_down(sw, o);
        zz += __shfl_down(zz, o);
    }
    if (t == 0) {
        flags[0] = (se >= 200) ? 1 : 0;
        flags[2] = (sw >= 200) ? 1 : 0;
        flags[1] = (zz >= 200) ? 1 : 0;
    }
}

static __device__ __forceinline__ int load_edge(const u32* __restrict__ ei, int is64,
                                                size_t flat_idx, int n) {
    int v = is64 ? (int)ei[2 * flat_idx] : (int)ei[flat_idx];
    if (v < 0) v = 0;
    if (v >= n) v = n - 1;
    return v;
}

// ---------------- zero ----------------
__global__ void k_zero(int* __restrict__ p, int count) {
    int i = blockIdx.x * 256 + threadIdx.x;
    if (i < count) p[i] = 0;
}

// ---------------- degree histogram over dst ----------------
__global__ void k_hist(const u32* __restrict__ ei, int E, int n,
                       const int* __restrict__ flags, int* __restrict__ hist) {
    int e = blockIdx.x * 256 + threadIdx.x;
    if (e >= E) return;
    int d = load_edge(ei, flags[1], (size_t)E + e, n);
    atomicAdd(&hist[d], 1);
}

// ---------------- 3-kernel exclusive scan ----------------
__global__ void k_scan1(const int* __restrict__ hist, int n,
                        int* __restrict__ incl, int* __restrict__ bsums) {
    __shared__ int s[256];
    int t = threadIdx.x;
    int i = blockIdx.x * 256 + t;
    int v = (i < n) ? hist[i] : 0;
    s[t] = v;
    __syncthreads();
    for (int d2 = 1; d2 < 256; d2 <<= 1) {
        int add = (t >= d2) ? s[t - d2] : 0;
        __syncthreads();
        s[t] += add;
        __syncthreads();
    }
    if (i < n) incl[i] = s[t];
    if (t == 255) bsums[blockIdx.x] = s[255];
}

__global__ void k_scan2(int* __restrict__ bsums, int nb) {
    __shared__ int s[256];
    int t = threadIdx.x;
    int v = (t < nb) ? bsums[t] : 0;
    s[t] = v;
    __syncthreads();
    for (int d2 = 1; d2 < 256; d2 <<= 1) {
        int add = (t >= d2) ? s[t - d2] : 0;
        __syncthreads();
        s[t] += add;
        __syncthreads();
    }
    if (t < nb) bsums[t] = s[t];
}

__global__ void k_scan3(const int* __restrict__ hist, const int* __restrict__ bsums,
                        int n, int* __restrict__ csr_off, float* __restrict__ dinv) {
    int i = blockIdx.x * 256 + threadIdx.x;
    if (i >= n) return;
    int b = blockIdx.x;
    int add = (b > 0) ? bsums[b - 1] : 0;
    int h = hist[i];
    csr_off[i] = add + csr_off[i] - h;
    dinv[i] = rsqrtf((float)(h + 1));
}

// ---------------- scatter edges into CSR pairs (src, norm) ----------------
__global__ void k_scatter(const u32* __restrict__ ei, int E, int n,
                          const int* __restrict__ flags,
                          const int* __restrict__ csr_off, int* __restrict__ csr_pos,
                          const float* __restrict__ dinv, int2* __restrict__ csr_pair) {
    int e = blockIdx.x * 256 + threadIdx.x;
    if (e >= E) return;
    int is64 = flags[1];
    int s = load_edge(ei, is64, (size_t)e, n);
    int d = load_edge(ei, is64, (size_t)E + e, n);
    int p = csr_off[d] + atomicAdd(&csr_pos[d], 1);
    if (p >= E) p = E - 1;
    csr_pair[p] = make_int2(s, __float_as_int(dinv[s] * dinv[d]));
}

// ---------------- x0: out slot1 = fp32(item_emb[-n:]) ----------------
__global__ void k_x0(const void* __restrict__ emb, int off_elems, int nD4,
                     const int* __restrict__ flags, float* __restrict__ out_x0) {
    int i = blockIdx.x * 256 + threadIdx.x;
    if (i >= nD4) return;
    float4 v;
    if (flags[0]) {
        ushort4 h = ((const ushort4*)((const u16*)emb + off_elems))[i];
        v = make_float4(bf2f(h.x), bf2f(h.y), bf2f(h.z), bf2f(h.w));
    } else {
        v = ((const float4*)((const float*)emb + off_elems))[i];
    }
    ((float4*)out_x0)[i] = v;
}

// ---------------- GEMM: Y(bf16-packed) = A(fp32) @ W_l ----------------
// 256 thr, 64 rows/block. thread (rowg=tid>>4, colg=tid&15) -> rows rowg*4..+3,
// col pairs {2colg+32j, +1 : j=0..3}. Y stored as u32 pack (lo=even col).
__global__ __launch_bounds__(256) void k_gemm(const float* __restrict__ A,
                                              const void* __restrict__ Wbase, int layer,
                                              const int* __restrict__ flags, int n,
                                              u32* __restrict__ Y) {
    __shared__ float Ws[D * D];  // 64 KB
    int tid = threadIdx.x;
    const size_t woff = (size_t)layer * D * D;
    if (flags[2]) {
        const ushort4* w4 = (const ushort4*)((const u16*)Wbase + woff);
#pragma unroll
        for (int j = 0; j < 16; j++) {
            int e = j * 1024 + tid * 4;
            ushort4 h = w4[j * 256 + tid];
            Ws[e + 0] = bf2f(h.x);
            Ws[e + 1] = bf2f(h.y);
            Ws[e + 2] = bf2f(h.z);
            Ws[e + 3] = bf2f(h.w);
        }
    } else {
        const float4* w4 = (const float4*)((const float*)Wbase + woff);
#pragma unroll
        for (int j = 0; j < 16; j++) {
            int e = j * 1024 + tid * 4;
            float4 v = w4[j * 256 + tid];
            Ws[e + 0] = v.x;
            Ws[e + 1] = v.y;
            Ws[e + 2] = v.z;
            Ws[e + 3] = v.w;
        }
    }
    __syncthreads();

    int rowg = tid >> 4, colg = tid & 15;
    int row0 = blockIdx.x * 64 + rowg * 4;

    float acc[4][4][2];
#pragma unroll
    for (int r = 0; r < 4; r++)
#pragma unroll
        for (int j = 0; j < 4; j++) acc[r][j][0] = acc[r][j][1] = 0.0f;

    const float4* a4[4];
#pragma unroll
    for (int r = 0; r < 4; r++) {
        int rr = row0 + r;
        if (rr >= n) rr = 0;
        a4[r] = (const float4*)(A + (size_t)rr * D);
    }

    for (int kk = 0; kk < 32; kk++) {
        float av[4][4];
#pragma unroll
        for (int r = 0; r < 4; r++) {
            float4 t = a4[r][kk];
            av[r][0] = t.x; av[r][1] = t.y; av[r][2] = t.z; av[r][3] = t.w;
        }
#pragma unroll
        for (int e = 0; e < 4; e++) {
            int k = kk * 4 + e;
            float2 w[4];
#pragma unroll
            for (int j = 0; j < 4; j++)
                w[j] = *(const float2*)&Ws[k * D + 2 * colg + 32 * j];
#pragma unroll
            for (int r = 0; r < 4; r++)
#pragma unroll
                for (int j = 0; j < 4; j++) {
                    acc[r][j][0] += av[r][e] * w[j].x;
                    acc[r][j][1] += av[r][e] * w[j].y;
                }
        }
    }

#pragma unroll
    for (int r = 0; r < 4; r++) {
        int rr = row0 + r;
        if (rr < n) {
#pragma unroll
            for (int j = 0; j < 4; j++) {
                u32 pack = (u32)f2bf(acc[r][j][0]) | ((u32)f2bf(acc[r][j][1]) << 16);
                Y[(size_t)rr * 64 + colg + 16 * j] = pack;
            }
        }
    }
}

// ---------------- aggregation: one WAVE per dst node, barrier-free ----------------
// 256-thr blocks = 4 independent waves. Lane t handles dims {2t, 2t+1}.
// Edge (src,norm) pairs broadcast via __shfl. Y is bf16-packed (256 B/row).
__global__ __launch_bounds__(256) void k_agg(const u32* __restrict__ Y,
                                             const int* __restrict__ csr_off,
                                             const int* __restrict__ cnt,
                                             const int2* __restrict__ csr_pair,
                                             const float* __restrict__ dinv,
                                             const void* __restrict__ bias_base, int layer,
                                             const int* __restrict__ flags, int n, int nD,
                                             const float* __restrict__ out_base,
                                             float* __restrict__ out_x,
                                             float* __restrict__ out_tot) {
    int i = blockIdx.x * 4 + (threadIdx.x >> 6);
    if (i >= n) return;
    int t = threadIdx.x & 63;

    float di = dinv[i];
    float di2 = di * di;
    u32 yv = Y[(size_t)i * 64 + t];
    float acc0 = bf2f((u16)(yv & 0xffffu)) * di2;  // self-loop
    float acc1 = bf2f((u16)(yv >> 16)) * di2;

    int start = csr_off[i];
    int c = cnt[i];

    for (int b = 0; b < c; b += 64) {
        int m = c - b;
        if (m > 64) m = 64;
        int2 pr = (t < m) ? csr_pair[start + b + t] : make_int2(0, 0);
        for (int j = 0; j < m; j++) {
            int s = __shfl(pr.x, j);
            float w = __uint_as_float((u32)__shfl(pr.y, j));
            u32 v = Y[(size_t)s * 64 + t];
            acc0 += bf2f((u16)(v & 0xffffu)) * w;
            acc1 += bf2f((u16)(v >> 16)) * w;
        }
    }

    float b0, b1;
    if (flags[0]) {
        const u16* bb = (const u16*)bias_base + layer * D;
        b0 = bf2f(bb[2 * t]);
        b1 = bf2f(bb[2 * t + 1]);
    } else {
        const float* bb = (const float*)bias_base + layer * D;
        b0 = bb[2 * t];
        b1 = bb[2 * t + 1];
    }
    float xv0 = acc0 + b0, xv1 = acc1 + b1;
    size_t base = (size_t)i * D + 2 * t;
    *(float2*)&out_x[base] = make_float2(xv0, xv1);

    if (out_tot) {  // layer 2: fuse total = x0+x1+x2+x3
        float2 s0 = *(const float2*)&out_base[(size_t)1 * nD + base];
        float2 s1 = *(const float2*)&out_base[(size_t)2 * nD + base];
        float2 s2 = *(const float2*)&out_base[(size_t)3 * nD + base];
        *(float2*)&out_tot[base] =
            make_float2(s0.x + s1.x + s2.x + xv0, s0.y + s1.y + s2.y + xv1);
    }
}

extern "C" void kernel_launch(void* const* d_in, const int* in_sizes, int n_in,
                              void* d_out, int out_size, void* d_ws, size_t ws_size,
                              hipStream_t stream) {
    float* out = (float*)d_out;              // fp32: [total, x0, x1, x2, x3]

    const int n = out_size / (5 * D);        // 50000

    // inputs identified by element count (robust to ordering)
    int i_emb = -1, i_ei = -1, i_w = -1, i_b = -1;
    {
        int order[8];
        int m = n_in > 8 ? 8 : n_in;
        for (int i = 0; i < m; i++) order[i] = i;
        for (int a = 0; a < m; a++)
            for (int b2 = a + 1; b2 < m; b2++)
                if (in_sizes[order[b2]] > in_sizes[order[a]]) {
                    int tmp = order[a]; order[a] = order[b2]; order[b2] = tmp;
                }
        i_emb = order[0];
        i_ei  = (m > 1) ? order[1] : 0;
        for (int i = 0; i < m; i++) {
            if (in_sizes[i] == 3 * D * D && i_w < 0) i_w = i;
            if (in_sizes[i] == 3 * D && i_b < 0) i_b = i;
        }
        if (i_w < 0) i_w = (m > 2) ? order[2] : 0;
        if (i_b < 0) i_b = (m > 3) ? order[3] : 0;
    }
    const void* emb  = d_in[i_emb];
    const void* wts  = d_in[i_w];
    const void* bias = d_in[i_b];
    const u32*  ei   = (const u32*)d_in[i_ei];

    const int E = in_sizes[i_ei] / 2;        // 600000
    const int rows = in_sizes[i_emb] / D;    // 80000
    const int off_elems = (rows - n) * D;

    char* p = (char*)d_ws;
    auto take = [&](size_t bytes) {
        char* r = p;
        p += (bytes + 255) & ~(size_t)255;
        return r;
    };
    int*   flags    = (int*)  take(3 * 4);
    int*   hist     = (int*)  take((size_t)n * 4);
    int*   csr_pos  = (int*)  take((size_t)n * 4);
    int*   csr_off  = (int*)  take((size_t)n * 4);
    int*   bsums    = (int*)  take(256 * 4);
    float* dinv     = (float*)take((size_t)n * 4);
    int2*  csr_pair = (int2*) take((size_t)E * 8);
    u32*   ybuf     = (u32*)  take((size_t)n * 64 * 4);  // bf16-packed Y
    // ~19 MB total (ws is ~512 MB)

    const int nD = n * D;
    const int nb = (n + 255) / 256;
    const int eb = (E + 255) / 256;

    k_probe<<<1, 64, 0, stream>>>((const u16*)emb, ei, (const u16*)wts, flags);
    k_zero<<<nb, 256, 0, stream>>>(hist, n);
    k_zero<<<nb, 256, 0, stream>>>(csr_pos, n);
    k_hist<<<eb, 256, 0, stream>>>(ei, E, n, flags, hist);
    k_scan1<<<nb, 256, 0, stream>>>(hist, n, csr_off, bsums);
    k_scan2<<<1, 256, 0, stream>>>(bsums, nb);
    k_scan3<<<nb, 256, 0, stream>>>(hist, bsums, n, csr_off, dinv);
    k_scatter<<<eb, 256, 0, stream>>>(ei, E, n, flags, csr_off, csr_pos, dinv, csr_pair);
    k_x0<<<(nD / 4 + 255) / 256, 256, 0, stream>>>(emb, off_elems, nD / 4, flags,
                                                   out + (size_t)nD);

    const int ab = (n + 3) / 4;  // 4 nodes (waves) per 256-thr block
    for (int l = 0; l < 3; l++) {
        const float* A = out + (size_t)(1 + l) * nD;   // x_l slot (fp32)
        float* ox = out + (size_t)(2 + l) * nD;        // x_{l+1} slot
        k_gemm<<<(n + 63) / 64, 256, 0, stream>>>(A, wts, l, flags, n, ybuf);
        k_agg<<<ab, 256, 0, stream>>>(ybuf, csr_off, hist, csr_pair, dinv, bias, l,
                                      flags, n, nD, out, ox,
                                      (l == 2) ? out : (float*)nullptr);
    }
}

// Round 8
// 407.330 us; speedup vs baseline: 1.3986x; 1.1462x over previous
//
#include <hip/hip_runtime.h>
#include <stdint.h>

#define D 128

typedef unsigned int u32;
typedef unsigned short u16;

static __device__ __forceinline__ float bf2f(u16 h) {
    return __uint_as_float(((u32)h) << 16);
}
static __device__ __forceinline__ u16 f2bf(float f) {
    u32 u = __float_as_uint(f);
    u32 r = (u + 0x7fffu + ((u >> 16) & 1u)) >> 16;  // round-to-nearest-even
    return (u16)r;
}
static __device__ __forceinline__ int clampi(int v, int n) {
    if (v < 0) v = 0;
    if (v >= n) v = n - 1;
    return v;
}

// ---------------- init: zero hist/csr_pos + dtype probe (block 0, wave 0) ----------------
// flags[0]=1 item_emb/biases bf16 else fp32; flags[1]=1 edges int64 else int32;
// flags[2]=1 weights bf16 else fp32
__global__ void k_init(int* __restrict__ hist, int* __restrict__ csr_pos, int n,
                       const u16* __restrict__ emb_raw, const u32* __restrict__ ei_raw,
                       const u16* __restrict__ w_raw, int* __restrict__ flags) {
    int i = blockIdx.x * 256 + threadIdx.x;
    if (i < n) {
        hist[i] = 0;
        csr_pos[i] = 0;
    }
    if (blockIdx.x == 0 && threadIdx.x < 64) {
        int t = threadIdx.x;
        int se = 0, sw = 0, zz = 0;
#pragma unroll
        for (int q = 0; q < 4; q++) {
            int k = t * 4 + q;  // 256 samples
            u16 he = emb_raw[2 * k];
            u32 exe = (he >> 7) & 0xFF;
            if (he == 0 || (exe >= 0x60 && exe <= 0x8F)) se++;
            u16 hw = w_raw[2 * k];
            u32 exw = (hw >> 7) & 0xFF;
            if (hw == 0 || (exw >= 0x60 && exw <= 0x8F)) sw++;
            if (ei_raw[2 * k + 1] == 0) zz++;
        }
#pragma unroll
        for (int o = 32; o; o >>= 1) {
            se += __shfl_down(se, o);
            sw += __shfl_down(sw, o);
            zz += __shfl_down(zz, o);
        }
        if (t == 0) {
            flags[0] = (se >= 200) ? 1 : 0;
            flags[2] = (sw >= 200) ? 1 : 0;
            flags[1] = (zz >= 200) ? 1 : 0;
        }
    }
}

// ---------------- degree histogram over dst ----------------
__global__ void k_hist(const u32* __restrict__ ei, int E, int n,
                       const int* __restrict__ flags, int* __restrict__ hist) {
    int e = blockIdx.x * 256 + threadIdx.x;
    if (e >= E) return;
    int d;
    if (flags[1]) d = ((const int2*)ei)[(size_t)E + e].x;  // int64: low word
    else          d = (int)ei[(size_t)E + e];
    atomicAdd(&hist[clampi(d, n)], 1);
}

// ---------------- scan1: per-block inclusive scan ----------------
__global__ void k_scan1(const int* __restrict__ hist, int n,
                        int* __restrict__ incl, int* __restrict__ bsums) {
    __shared__ int s[256];
    int t = threadIdx.x;
    int i = blockIdx.x * 256 + t;
    int v = (i < n) ? hist[i] : 0;
    s[t] = v;
    __syncthreads();
    for (int d2 = 1; d2 < 256; d2 <<= 1) {
        int add = (t >= d2) ? s[t - d2] : 0;
        __syncthreads();
        s[t] += add;
        __syncthreads();
    }
    if (i < n) incl[i] = s[t];
    if (t == 255) bsums[blockIdx.x] = s[255];
}

// ---------------- scan23: each block reduces its own bsums prefix, finalizes ----------------
__global__ void k_scan23(const int* __restrict__ hist, const int* __restrict__ bsums,
                         int n, int* __restrict__ csr_off, float* __restrict__ dinv) {
    __shared__ int s[256];
    int t = threadIdx.x, b = blockIdx.x;
    s[t] = (t < b) ? bsums[t] : 0;  // t<b<nb so in-bounds
    __syncthreads();
    for (int o = 128; o; o >>= 1) {
        if (t < o) s[t] += s[t + o];
        __syncthreads();
    }
    int add = s[0];
    int i = b * 256 + t;
    if (i < n) {
        int h = hist[i];
        csr_off[i] = add + csr_off[i] - h;  // incl -> excl + block offset
        dinv[i] = rsqrtf((float)(h + 1));   // +1 self-loop
    }
}

// ---------------- fused scatter (blocks [0,eb)) + x0 copy (blocks [eb,..)) ----------------
__global__ void k_sx(const u32* __restrict__ ei, int E, int n,
                     const int* __restrict__ flags,
                     const int* __restrict__ csr_off, int* __restrict__ csr_pos,
                     const float* __restrict__ dinv, int2* __restrict__ csr_pair,
                     const void* __restrict__ emb, int off_elems, int nD4,
                     float* __restrict__ out_x0, int eb) {
    int bid = blockIdx.x;
    if (bid < eb) {
        int e = bid * 256 + threadIdx.x;
        if (e >= E) return;
        int s, d;
        if (flags[1]) {
            s = ((const int2*)ei)[e].x;
            d = ((const int2*)ei)[(size_t)E + e].x;
        } else {
            s = (int)ei[e];
            d = (int)ei[(size_t)E + e];
        }
        s = clampi(s, n);
        d = clampi(d, n);
        int p = csr_off[d] + atomicAdd(&csr_pos[d], 1);
        if (p >= E) p = E - 1;
        csr_pair[p] = make_int2(s, __float_as_int(dinv[s] * dinv[d]));
    } else {
        int i = (bid - eb) * 256 + threadIdx.x;
        if (i >= nD4) return;
        float4 v;
        if (flags[0]) {
            ushort4 h = ((const ushort4*)((const u16*)emb + off_elems))[i];
            v = make_float4(bf2f(h.x), bf2f(h.y), bf2f(h.z), bf2f(h.w));
        } else {
            v = ((const float4*)((const float*)emb + off_elems))[i];
        }
        ((float4*)out_x0)[i] = v;
    }
}

// ---------------- GEMM: Y(bf16-packed) = A(fp32) @ W_l ----------------
// 256 thr, 64 rows/block. thread (rowg=tid>>4, colg=tid&15) -> rows rowg*4..+3,
// col pairs {2colg+32j, +1 : j=0..3}. Y stored as u32 pack (lo=even col).
__global__ __launch_bounds__(256) void k_gemm(const float* __restrict__ A,
                                              const void* __restrict__ Wbase, int layer,
                                              const int* __restrict__ flags, int n,
                                              u32* __restrict__ Y) {
    __shared__ float Ws[D * D];  // 64 KB
    int tid = threadIdx.x;
    const size_t woff = (size_t)layer * D * D;
    if (flags[2]) {
        const ushort4* w4 = (const ushort4*)((const u16*)Wbase + woff);
#pragma unroll
        for (int j = 0; j < 16; j++) {
            int e = j * 1024 + tid * 4;
            ushort4 h = w4[j * 256 + tid];
            Ws[e + 0] = bf2f(h.x);
            Ws[e + 1] = bf2f(h.y);
            Ws[e + 2] = bf2f(h.z);
            Ws[e + 3] = bf2f(h.w);
        }
    } else {
        const float4* w4 = (const float4*)((const float*)Wbase + woff);
#pragma unroll
        for (int j = 0; j < 16; j++) {
            int e = j * 1024 + tid * 4;
            float4 v = w4[j * 256 + tid];
            Ws[e + 0] = v.x;
            Ws[e + 1] = v.y;
            Ws[e + 2] = v.z;
            Ws[e + 3] = v.w;
        }
    }
    __syncthreads();

    int rowg = tid >> 4, colg = tid & 15;
    int row0 = blockIdx.x * 64 + rowg * 4;

    float acc[4][4][2];
#pragma unroll
    for (int r = 0; r < 4; r++)
#pragma unroll
        for (int j = 0; j < 4; j++) acc[r][j][0] = acc[r][j][1] = 0.0f;

    const float4* a4[4];
#pragma unroll
    for (int r = 0; r < 4; r++) {
        int rr = row0 + r;
        if (rr >= n) rr = 0;
        a4[r] = (const float4*)(A + (size_t)rr * D);
    }

    for (int kk = 0; kk < 32; kk++) {
        float av[4][4];
#pragma unroll
        for (int r = 0; r < 4; r++) {
            float4 t = a4[r][kk];
            av[r][0] = t.x; av[r][1] = t.y; av[r][2] = t.z; av[r][3] = t.w;
        }
#pragma unroll
        for (int e = 0; e < 4; e++) {
            int k = kk * 4 + e;
            float2 w[4];
#pragma unroll
            for (int j = 0; j < 4; j++)
                w[j] = *(const float2*)&Ws[k * D + 2 * colg + 32 * j];
#pragma unroll
            for (int r = 0; r < 4; r++)
#pragma unroll
                for (int j = 0; j < 4; j++) {
                    acc[r][j][0] += av[r][e] * w[j].x;
                    acc[r][j][1] += av[r][e] * w[j].y;
                }
        }
    }

#pragma unroll
    for (int r = 0; r < 4; r++) {
        int rr = row0 + r;
        if (rr < n) {
#pragma unroll
            for (int j = 0; j < 4; j++) {
                u32 pack = (u32)f2bf(acc[r][j][0]) | ((u32)f2bf(acc[r][j][1]) << 16);
                Y[(size_t)rr * 64 + colg + 16 * j] = pack;
            }
        }
    }
}

// ---------------- aggregation: one WAVE per dst node, barrier-free, unrolled x4 ----------------
// 256-thr blocks = 4 independent waves. Lane t handles dims {2t, 2t+1}.
// Edge (src,norm) broadcast via __shfl; 4 gathers in flight, 2 acc pairs.
__global__ __launch_bounds__(256) void k_agg(const u32* __restrict__ Y,
                                             const int* __restrict__ csr_off,
                                             const int* __restrict__ cnt,
                                             const int2* __restrict__ csr_pair,
                                             const float* __restrict__ dinv,
                                             const void* __restrict__ bias_base, int layer,
                                             const int* __restrict__ flags, int n, int nD,
                                             const float* __restrict__ out_base,
                                             float* __restrict__ out_x,
                                             float* __restrict__ out_tot) {
    int i = blockIdx.x * 4 + (threadIdx.x >> 6);
    if (i >= n) return;
    int t = threadIdx.x & 63;

    float di = dinv[i];
    float di2 = di * di;
    u32 yv = Y[(size_t)i * 64 + t];
    float a0 = bf2f((u16)(yv & 0xffffu)) * di2;  // self-loop
    float a1 = bf2f((u16)(yv >> 16)) * di2;
    float c0 = 0.0f, c1 = 0.0f;                  // second acc pair

    int start = csr_off[i];
    int c = cnt[i];

    for (int base = 0; base < c; base += 64) {
        int m = c - base;
        if (m > 64) m = 64;
        int2 pr = (t < m) ? csr_pair[start + base + t] : make_int2(0, 0);
        int j = 0;
        for (; j + 3 < m; j += 4) {
            int s0 = __shfl(pr.x, j);
            int s1 = __shfl(pr.x, j + 1);
            int s2 = __shfl(pr.x, j + 2);
            int s3 = __shfl(pr.x, j + 3);
            float w0 = __uint_as_float((u32)__shfl(pr.y, j));
            float w1 = __uint_as_float((u32)__shfl(pr.y, j + 1));
            float w2 = __uint_as_float((u32)__shfl(pr.y, j + 2));
            float w3 = __uint_as_float((u32)__shfl(pr.y, j + 3));
            u32 v0 = Y[(size_t)s0 * 64 + t];
            u32 v1 = Y[(size_t)s1 * 64 + t];
            u32 v2 = Y[(size_t)s2 * 64 + t];
            u32 v3 = Y[(size_t)s3 * 64 + t];
            a0 += bf2f((u16)(v0 & 0xffffu)) * w0;
            a1 += bf2f((u16)(v0 >> 16)) * w0;
            c0 += bf2f((u16)(v1 & 0xffffu)) * w1;
            c1 += bf2f((u16)(v1 >> 16)) * w1;
            a0 += bf2f((u16)(v2 & 0xffffu)) * w2;
            a1 += bf2f((u16)(v2 >> 16)) * w2;
            c0 += bf2f((u16)(v3 & 0xffffu)) * w3;
            c1 += bf2f((u16)(v3 >> 16)) * w3;
        }
        for (; j < m; j++) {
            int s = __shfl(pr.x, j);
            float w = __uint_as_float((u32)__shfl(pr.y, j));
            u32 v = Y[(size_t)s * 64 + t];
            a0 += bf2f((u16)(v & 0xffffu)) * w;
            a1 += bf2f((u16)(v >> 16)) * w;
        }
    }
    float acc0 = a0 + c0, acc1 = a1 + c1;

    float b0, b1;
    if (flags[0]) {
        const u16* bb = (const u16*)bias_base + layer * D;
        b0 = bf2f(bb[2 * t]);
        b1 = bf2f(bb[2 * t + 1]);
    } else {
        const float* bb = (const float*)bias_base + layer * D;
        b0 = bb[2 * t];
        b1 = bb[2 * t + 1];
    }
    float xv0 = acc0 + b0, xv1 = acc1 + b1;
    size_t base = (size_t)i * D + 2 * t;
    *(float2*)&out_x[base] = make_float2(xv0, xv1);

    if (out_tot) {  // layer 2: fuse total = x0+x1+x2+x3
        float2 s0 = *(const float2*)&out_base[(size_t)1 * nD + base];
        float2 s1 = *(const float2*)&out_base[(size_t)2 * nD + base];
        float2 s2 = *(const float2*)&out_base[(size_t)3 * nD + base];
        *(float2*)&out_tot[base] =
            make_float2(s0.x + s1.x + s2.x + xv0, s0.y + s1.y + s2.y + xv1);
    }
}

extern "C" void kernel_launch(void* const* d_in, const int* in_sizes, int n_in,
                              void* d_out, int out_size, void* d_ws, size_t ws_size,
                              hipStream_t stream) {
    float* out = (float*)d_out;              // fp32: [total, x0, x1, x2, x3]

    const int n = out_size / (5 * D);        // 50000

    // inputs identified by element count (robust to ordering)
    int i_emb = -1, i_ei = -1, i_w = -1, i_b = -1;
    {
        int order[8];
        int m = n_in > 8 ? 8 : n_in;
        for (int i = 0; i < m; i++) order[i] = i;
        for (int a = 0; a < m; a++)
            for (int b2 = a + 1; b2 < m; b2++)
                if (in_sizes[order[b2]] > in_sizes[order[a]]) {
                    int tmp = order[a]; order[a] = order[b2]; order[b2] = tmp;
                }
        i_emb = order[0];
        i_ei  = (m > 1) ? order[1] : 0;
        for (int i = 0; i < m; i++) {
            if (in_sizes[i] == 3 * D * D && i_w < 0) i_w = i;
            if (in_sizes[i] == 3 * D && i_b < 0) i_b = i;
        }
        if (i_w < 0) i_w = (m > 2) ? order[2] : 0;
        if (i_b < 0) i_b = (m > 3) ? order[3] : 0;
    }
    const void* emb  = d_in[i_emb];
    const void* wts  = d_in[i_w];
    const void* bias = d_in[i_b];
    const u32*  ei   = (const u32*)d_in[i_ei];

    const int E = in_sizes[i_ei] / 2;        // 600000
    const int rows = in_sizes[i_emb] / D;    // 80000
    const int off_elems = (rows - n) * D;

    char* p = (char*)d_ws;
    auto take = [&](size_t bytes) {
        char* r = p;
        p += (bytes + 255) & ~(size_t)255;
        return r;
    };
    int*   flags    = (int*)  take(3 * 4);
    int*   hist     = (int*)  take((size_t)n * 4);
    int*   csr_pos  = (int*)  take((size_t)n * 4);
    int*   csr_off  = (int*)  take((size_t)n * 4);
    int*   bsums    = (int*)  take(256 * 4);
    float* dinv     = (float*)take((size_t)n * 4);
    int2*  csr_pair = (int2*) take((size_t)E * 8);
    u32*   ybuf     = (u32*)  take((size_t)n * 64 * 4);  // bf16-packed Y

    const int nD = n * D;
    const int nb = (n + 255) / 256;          // 196 (<=256 required by scan23)
    const int eb = (E + 255) / 256;
    const int x0b = (nD / 4 + 255) / 256;

    k_init<<<nb, 256, 0, stream>>>(hist, csr_pos, n, (const u16*)emb, ei,
                                   (const u16*)wts, flags);
    k_hist<<<eb, 256, 0, stream>>>(ei, E, n, flags, hist);
    k_scan1<<<nb, 256, 0, stream>>>(hist, n, csr_off, bsums);
    k_scan23<<<nb, 256, 0, stream>>>(hist, bsums, n, csr_off, dinv);
    k_sx<<<eb + x0b, 256, 0, stream>>>(ei, E, n, flags, csr_off, csr_pos, dinv,
                                       csr_pair, emb, off_elems, nD / 4,
                                       out + (size_t)nD, eb);

    const int ab = (n + 3) / 4;  // 4 nodes (waves) per 256-thr block
    for (int l = 0; l < 3; l++) {
        const float* A = out + (size_t)(1 + l) * nD;   // x_l slot (fp32)
        float* ox = out + (size_t)(2 + l) * nD;        // x_{l+1} slot
        k_gemm<<<(n + 63) / 64, 256, 0, stream>>>(A, wts, l, flags, n, ybuf);
        k_agg<<<ab, 256, 0, stream>>>(ybuf, csr_off, hist, csr_pair, dinv, bias, l,
                                      flags, n, nD, out, ox,
                                      (l == 2) ? out : (float*)nullptr);
    }
}